// Round 14
// baseline (459.361 us; speedup 1.0000x reference)
//
#include <hip/hip_runtime.h>
#include <hip/hip_bf16.h>

#define NN 100000
#define NE 1600000
#define NODE_D 64
#define EDGE_D 48
#define E16 64   // padded ea16 row stride (bf16) = 128B = one full cache line
#define U_D 32
#define IN_D 144
#define HID 128
#define OUT_D 64
#define BM 64
#define S0 152   // act row stride (ushort cols)
#define SCAN_BS 1024
#define SCAN_NB ((NN + SCAN_BS - 1) / SCAN_BS)  // 98
#define W1K 160  // padded k-stride of packed W1 (zeros for k>=144)
#define NW1 (HID * W1K)      // 20480
#define NW2 (HID * HID)      // 16384
#define NW3 (OUT_D * HID)    // 8192
#define NWTOT (NW1 + NW2 + NW3)  // 45056
#define IDS 1536             // ids LDS capacity (mean 1024 + margin)

typedef __attribute__((ext_vector_type(8))) short bf16x8;
typedef __attribute__((ext_vector_type(4))) float f32x4;
typedef __attribute__((ext_vector_type(4))) unsigned int u32x4;

__device__ __forceinline__ short f2bs(float f) {
  union { __hip_bfloat16 h; short s; } v;
  v.h = __float2bfloat16(f);
  return v.s;
}
__device__ __forceinline__ float blo(unsigned int pk) {
  union { unsigned int u; float f; } v; v.u = pk << 16; return v.f;
}
__device__ __forceinline__ float bhi(unsigned int pk) {
  union { unsigned int u; float f; } v; v.u = pk & 0xffff0000u; return v.f;
}

__device__ __forceinline__ void st4(unsigned short* p, float4 v) {
  unsigned a = (unsigned)(unsigned short)f2bs(v.x) | ((unsigned)(unsigned short)f2bs(v.y) << 16);
  unsigned b = (unsigned)(unsigned short)f2bs(v.z) | ((unsigned)(unsigned short)f2bs(v.w) << 16);
  *reinterpret_cast<uint2*>(p) = make_uint2(a, b);
}

// ---------------- setup: zero hist (blocks 0..97) + pack weights ----------------
__global__ __launch_bounds__(256) void setup_kernel(
    int* __restrict__ hist,
    const float* __restrict__ W1, const float* __restrict__ W2,
    const float* __restrict__ W3, unsigned short* __restrict__ Wp) {
  const int b = blockIdx.x, tid = threadIdx.x;
  if (b < SCAN_NB) {
    int base = b * SCAN_BS + tid * 4;
    if (base + 3 < NN) {
      *reinterpret_cast<int4*>(&hist[base]) = make_int4(0, 0, 0, 0);
    } else {
      for (int k = 0; k < 4; ++k)
        if (base + k < NN) hist[base + k] = 0;
    }
    return;
  }
  int gid = (b - SCAN_NB) * 256 + tid;
  if (gid >= NWTOT) return;
  float v;
  if (gid < NW1) {
    int n = gid / W1K, k = gid - n * W1K;
    v = (k < IN_D) ? W1[(size_t)k * HID + n] : 0.f;
  } else if (gid < NW1 + NW2) {
    int i2 = gid - NW1;
    int n = i2 >> 7, k = i2 & 127;
    v = W2[(size_t)k * HID + n];
  } else {
    int i3 = gid - NW1 - NW2;
    int n = i3 >> 7, k = i3 & 127;
    v = W3[(size_t)k * OUT_D + n];
  }
  Wp[gid] = (unsigned short)f2bs(v);
}

// ---------------- hist + sequential bf16 pack (one full line per edge) ----------------
__global__ __launch_bounds__(256) void hist_pack_kernel(
    const int* __restrict__ src, const float* __restrict__ ea,
    int* __restrict__ hist, unsigned short* __restrict__ ea16) {
  int e = blockIdx.x * 256 + threadIdx.x;
  if (e >= NE) return;
  atomicAdd(&hist[src[e]], 1);
  const f32x4* rp = reinterpret_cast<const f32x4*>(ea + (size_t)e * EDGE_D);
  f32x4 v[12];
#pragma unroll
  for (int k = 0; k < 12; ++k) v[k] = __builtin_nontemporal_load(rp + k);
  u32x4* dp = reinterpret_cast<u32x4*>(ea16 + (size_t)e * E16);
#pragma unroll
  for (int k = 0; k < 6; ++k) {
    u32x4 w;
    w.x = (unsigned)(unsigned short)f2bs(v[2 * k].x) |
          ((unsigned)(unsigned short)f2bs(v[2 * k].y) << 16);
    w.y = (unsigned)(unsigned short)f2bs(v[2 * k].z) |
          ((unsigned)(unsigned short)f2bs(v[2 * k].w) << 16);
    w.z = (unsigned)(unsigned short)f2bs(v[2 * k + 1].x) |
          ((unsigned)(unsigned short)f2bs(v[2 * k + 1].y) << 16);
    w.w = (unsigned)(unsigned short)f2bs(v[2 * k + 1].z) |
          ((unsigned)(unsigned short)f2bs(v[2 * k + 1].w) << 16);
    dp[k] = w;
  }
  u32x4 z = {0u, 0u, 0u, 0u};
  dp[6] = z;
  dp[7] = z;
}

// ---------------- scan 2a ----------------
__global__ __launch_bounds__(256) void bsum_kernel(const int* __restrict__ hist,
                                                   int* __restrict__ bsum) {
  const int b = blockIdx.x, tid = threadIdx.x;
  const int base = b * SCAN_BS + tid * 4;
  int4 v = make_int4(0, 0, 0, 0);
  if (base + 3 < NN) v = *reinterpret_cast<const int4*>(&hist[base]);
  else {
    int t[4] = {0, 0, 0, 0};
    for (int k = 0; k < 4; ++k) if (base + k < NN) t[k] = hist[base + k];
    v = make_int4(t[0], t[1], t[2], t[3]);
  }
  int s = v.x + v.y + v.z + v.w;
  for (int d = 32; d; d >>= 1) s += __shfl_down(s, d, 64);
  __shared__ int ws[4];
  if ((tid & 63) == 0) ws[tid >> 6] = s;
  __syncthreads();
  if (tid == 0) bsum[b] = ws[0] + ws[1] + ws[2] + ws[3];
}

// ---------------- scan 2b ----------------
__global__ __launch_bounds__(128) void bscan_kernel(const int* __restrict__ bsum,
                                                    int* __restrict__ bpre) {
  const int t = threadIdx.x;
  const int lane = t & 63, wave = t >> 6;
  int v = (t < SCAN_NB) ? bsum[t] : 0;
  int incl = v;
  for (int d = 1; d < 64; d <<= 1) {
    int q = __shfl_up(incl, d, 64);
    if (lane >= d) incl += q;
  }
  __shared__ int wtot[2];
  if (lane == 63) wtot[wave] = incl;
  __syncthreads();
  int add = (wave == 1) ? wtot[0] : 0;
  if (t < SCAN_NB) bpre[t] = incl - v + add;
}

// ---------------- scan 2c ----------------
__global__ __launch_bounds__(256) void offsets_kernel(const int* __restrict__ hist,
                                                      const int* __restrict__ bpre,
                                                      int* __restrict__ offsets,
                                                      int* __restrict__ cursor) {
  const int b = blockIdx.x, tid = threadIdx.x;
  const int base = b * SCAN_BS + tid * 4;
  const int lane = tid & 63, wave = tid >> 6;
  int4 v = make_int4(0, 0, 0, 0);
  if (base + 3 < NN) v = *reinterpret_cast<const int4*>(&hist[base]);
  else {
    int t[4] = {0, 0, 0, 0};
    for (int k = 0; k < 4; ++k) if (base + k < NN) t[k] = hist[base + k];
    v = make_int4(t[0], t[1], t[2], t[3]);
  }
  const int tsum = v.x + v.y + v.z + v.w;
  int incl = tsum;
  for (int d = 1; d < 64; d <<= 1) {
    int q = __shfl_up(incl, d, 64);
    if (lane >= d) incl += q;
  }
  __shared__ int ws[4];
  __shared__ int wpre[4];
  if (lane == 63) ws[wave] = incl;
  __syncthreads();
  if (tid == 0) {
    int r = 0;
    for (int w = 0; w < 4; ++w) { wpre[w] = r; r += ws[w]; }
  }
  __syncthreads();
  int run = bpre[b] + wpre[wave] + incl - tsum;
  int vals[4] = {v.x, v.y, v.z, v.w};
  for (int k = 0; k < 4; ++k) {
    int i = base + k;
    if (i < NN) { offsets[i] = run; cursor[i] = run; run += vals[k]; }
  }
}

// ---------------- permute: 4 edges/thread id-scatter (L2-resident dst) ----------------
__global__ __launch_bounds__(256) void permute_kernel(const int* __restrict__ src,
                                                      int* __restrict__ cursor,
                                                      int* __restrict__ perm) {
  int i = blockIdx.x * 256 + threadIdx.x;
  if (i * 4 >= NE) return;
  int4 s = reinterpret_cast<const int4*>(src)[i];
  const int e = i * 4;
  int p0 = atomicAdd(&cursor[s.x], 1);
  int p1 = atomicAdd(&cursor[s.y], 1);
  int p2 = atomicAdd(&cursor[s.z], 1);
  int p3 = atomicAdd(&cursor[s.w], 1);
  perm[p0] = e + 0;
  perm[p1] = e + 1;
  perm[p2] = e + 2;
  perm[p3] = e + 3;
}

// ---------------- fused: perm-indirect 1-line bf16 gather + concat + MLP ----------------
__global__ __launch_bounds__(256) void fused_kernel(
    const float* __restrict__ x, const unsigned short* __restrict__ ea16,
    const float* __restrict__ u, const int* __restrict__ batch,
    const int* __restrict__ perm, const int* __restrict__ hist,
    const int* __restrict__ offsets, const unsigned short* __restrict__ Wp,
    const float* __restrict__ b1, const float* __restrict__ b2,
    const float* __restrict__ b3, float* __restrict__ out) {
  __shared__ __align__(16) unsigned short act[BM][S0];  // comb -> h1 -> h2
  __shared__ int ids[IDS];

  const int tid = threadIdx.x;
  const int lane = tid & 63;
  const int wid = tid >> 6;
  const int lr = lane & 15;
  const int lg = lane >> 4;
  const int node0 = blockIdx.x * BM;

  const unsigned short* Wp1 = Wp;                 // [HID][W1K]
  const unsigned short* Wp2 = Wp + NW1;           // [HID][HID]
  const unsigned short* Wp3 = Wp + NW1 + NW2;     // [OUT_D][HID]

  const bf16x8 az = {0, 0, 0, 0, 0, 0, 0, 0};

  // ---- stage block's edge-id range into LDS ----
  const int start = offsets[node0];
  const int end = (node0 + BM < NN) ? offsets[node0 + BM] : NE;
  const int L = end - start;
  for (int i = tid; i < L && i < IDS; i += 256)
    ids[i] = perm[start + i];

  // ---- stage x and u parts of comb ----
  for (int i = tid; i < BM * (NODE_D / 4); i += 256) {
    int r = i >> 4, q = i & 15;
    int node = node0 + r;
    float4 v = make_float4(0.f, 0.f, 0.f, 0.f);
    if (node < NN) v = reinterpret_cast<const float4*>(x)[(size_t)node * 16 + q];
    st4(&act[r][q * 4], v);
  }
  for (int i = tid; i < BM * (U_D / 4); i += 256) {
    int r = i >> 3, q = i & 7;
    int node = node0 + r;
    float4 v = make_float4(0.f, 0.f, 0.f, 0.f);
    if (node < NN) {
      int b = batch[node];
      v = reinterpret_cast<const float4*>(u)[(size_t)b * 8 + q];
    }
    st4(&act[r][NODE_D + EDGE_D + q * 4], v);
  }
  __syncthreads();

  // ---- gather: 16-lane group per node; each edge = one 128B line, 8 in flight ----
  {
    const int g = tid >> 4;        // group 0..15
    const int c = tid & 15;        // uint2 column 0..15 (cols 12-15 read zero pad)
    for (int i = 0; i < 4; ++i) {
      const int nl = g * 4 + i;
      const int node = node0 + nl;
      int deg = 0, sl = 0;
      if (node < NN) { deg = hist[node]; sl = offsets[node] - start; }
      const unsigned short* bc = ea16 + c * 4;
      float4 a0 = make_float4(0.f, 0.f, 0.f, 0.f);
      float4 a1 = make_float4(0.f, 0.f, 0.f, 0.f);
      int j = 0;
      for (; j + 7 < deg; j += 8) {
        int p = sl + j;
        int e0 = (p + 0 < IDS) ? ids[p + 0] : perm[start + p + 0];
        int e1 = (p + 1 < IDS) ? ids[p + 1] : perm[start + p + 1];
        int e2 = (p + 2 < IDS) ? ids[p + 2] : perm[start + p + 2];
        int e3 = (p + 3 < IDS) ? ids[p + 3] : perm[start + p + 3];
        int e4 = (p + 4 < IDS) ? ids[p + 4] : perm[start + p + 4];
        int e5 = (p + 5 < IDS) ? ids[p + 5] : perm[start + p + 5];
        int e6 = (p + 6 < IDS) ? ids[p + 6] : perm[start + p + 6];
        int e7 = (p + 7 < IDS) ? ids[p + 7] : perm[start + p + 7];
        uint2 w0 = *reinterpret_cast<const uint2*>(bc + (size_t)e0 * E16);
        uint2 w1 = *reinterpret_cast<const uint2*>(bc + (size_t)e1 * E16);
        uint2 w2 = *reinterpret_cast<const uint2*>(bc + (size_t)e2 * E16);
        uint2 w3 = *reinterpret_cast<const uint2*>(bc + (size_t)e3 * E16);
        uint2 w4 = *reinterpret_cast<const uint2*>(bc + (size_t)e4 * E16);
        uint2 w5 = *reinterpret_cast<const uint2*>(bc + (size_t)e5 * E16);
        uint2 w6 = *reinterpret_cast<const uint2*>(bc + (size_t)e6 * E16);
        uint2 w7 = *reinterpret_cast<const uint2*>(bc + (size_t)e7 * E16);
        a0.x += blo(w0.x) + blo(w1.x) + blo(w2.x) + blo(w3.x);
        a0.y += bhi(w0.x) + bhi(w1.x) + bhi(w2.x) + bhi(w3.x);
        a0.z += blo(w0.y) + blo(w1.y) + blo(w2.y) + blo(w3.y);
        a0.w += bhi(w0.y) + bhi(w1.y) + bhi(w2.y) + bhi(w3.y);
        a1.x += blo(w4.x) + blo(w5.x) + blo(w6.x) + blo(w7.x);
        a1.y += bhi(w4.x) + bhi(w5.x) + bhi(w6.x) + bhi(w7.x);
        a1.z += blo(w4.y) + blo(w5.y) + blo(w6.y) + blo(w7.y);
        a1.w += bhi(w4.y) + bhi(w5.y) + bhi(w6.y) + bhi(w7.y);
      }
      for (; j < deg; ++j) {
        int p = sl + j;
        int e0 = (p < IDS) ? ids[p] : perm[start + p];
        uint2 w0 = *reinterpret_cast<const uint2*>(bc + (size_t)e0 * E16);
        a0.x += blo(w0.x); a0.y += bhi(w0.x);
        a0.z += blo(w0.y); a0.w += bhi(w0.y);
      }
      float inv = (deg > 0) ? 1.0f / (float)deg : 0.0f;
      if (c < 12 && node < NN)
        st4(&act[nl][NODE_D + c * 4],
            make_float4((a0.x + a1.x) * inv, (a0.y + a1.y) * inv,
                        (a0.z + a1.z) * inv, (a0.w + a1.w) * inv));
    }
  }
  __syncthreads();

  // ---- layer 1: [64,144] @ [144,128] + b1, relu ----
  {
    const int n0 = wid * 32;
    bf16x8 wf[5][2];
#pragma unroll
    for (int t = 0; t < 5; ++t)
#pragma unroll
      for (int nf = 0; nf < 2; ++nf)
        wf[t][nf] = *reinterpret_cast<const bf16x8*>(
            &Wp1[(size_t)(n0 + nf * 16 + lr) * W1K + t * 32 + lg * 8]);
    float bias0 = b1[n0 + lr], bias1 = b1[n0 + 16 + lr];
    f32x4 acc[4][2];
#pragma unroll
    for (int mf = 0; mf < 4; ++mf) {
      acc[mf][0] = (f32x4){bias0, bias0, bias0, bias0};
      acc[mf][1] = (f32x4){bias1, bias1, bias1, bias1};
    }
#pragma unroll
    for (int t = 0; t < 5; ++t) {
#pragma unroll
      for (int mf = 0; mf < 4; ++mf) {
        bf16x8 a;
        if (t < 4) {
          a = *reinterpret_cast<const bf16x8*>(&act[mf * 16 + lr][t * 32 + lg * 8]);
        } else {
          a = az;
          if (lg < 2)
            a = *reinterpret_cast<const bf16x8*>(&act[mf * 16 + lr][128 + lg * 8]);
        }
        acc[mf][0] = __builtin_amdgcn_mfma_f32_16x16x32_bf16(a, wf[t][0], acc[mf][0], 0, 0, 0);
        acc[mf][1] = __builtin_amdgcn_mfma_f32_16x16x32_bf16(a, wf[t][1], acc[mf][1], 0, 0, 0);
      }
    }
    __syncthreads();  // all waves done reading comb (and ids dead)
#pragma unroll
    for (int mf = 0; mf < 4; ++mf)
#pragma unroll
      for (int nf = 0; nf < 2; ++nf)
#pragma unroll
        for (int r = 0; r < 4; ++r)
          act[mf * 16 + lg * 4 + r][n0 + nf * 16 + lr] =
              (unsigned short)f2bs(fmaxf(acc[mf][nf][r], 0.f));
  }
  __syncthreads();

  // ---- layer 2: [64,128] @ [128,128] + b2, relu ----
  {
    const int n0 = wid * 32;
    bf16x8 wf[4][2];
#pragma unroll
    for (int t = 0; t < 4; ++t)
#pragma unroll
      for (int nf = 0; nf < 2; ++nf)
        wf[t][nf] = *reinterpret_cast<const bf16x8*>(
            &Wp2[(size_t)(n0 + nf * 16 + lr) * HID + t * 32 + lg * 8]);
    float bias0 = b2[n0 + lr], bias1 = b2[n0 + 16 + lr];
    f32x4 acc[4][2];
#pragma unroll
    for (int mf = 0; mf < 4; ++mf) {
      acc[mf][0] = (f32x4){bias0, bias0, bias0, bias0};
      acc[mf][1] = (f32x4){bias1, bias1, bias1, bias1};
    }
#pragma unroll
    for (int t = 0; t < 4; ++t) {
#pragma unroll
      for (int mf = 0; mf < 4; ++mf) {
        bf16x8 a = *reinterpret_cast<const bf16x8*>(&act[mf * 16 + lr][t * 32 + lg * 8]);
        acc[mf][0] = __builtin_amdgcn_mfma_f32_16x16x32_bf16(a, wf[t][0], acc[mf][0], 0, 0, 0);
        acc[mf][1] = __builtin_amdgcn_mfma_f32_16x16x32_bf16(a, wf[t][1], acc[mf][1], 0, 0, 0);
      }
    }
    __syncthreads();  // all waves done reading h1
#pragma unroll
    for (int mf = 0; mf < 4; ++mf)
#pragma unroll
      for (int nf = 0; nf < 2; ++nf)
#pragma unroll
        for (int r = 0; r < 4; ++r)
          act[mf * 16 + lg * 4 + r][n0 + nf * 16 + lr] =
              (unsigned short)f2bs(fmaxf(acc[mf][nf][r], 0.f));
  }
  __syncthreads();

  // ---- layer 3: [64,128] @ [128,64] + b3 -> out (f32) ----
  {
    const int n0 = wid * 16;
    bf16x8 wf[4];
#pragma unroll
    for (int t = 0; t < 4; ++t)
      wf[t] = *reinterpret_cast<const bf16x8*>(
          &Wp3[(size_t)(n0 + lr) * HID + t * 32 + lg * 8]);
    float bias = b3[n0 + lr];
    f32x4 acc[4];
#pragma unroll
    for (int mf = 0; mf < 4; ++mf) acc[mf] = (f32x4){bias, bias, bias, bias};
#pragma unroll
    for (int t = 0; t < 4; ++t) {
#pragma unroll
      for (int mf = 0; mf < 4; ++mf) {
        bf16x8 a = *reinterpret_cast<const bf16x8*>(&act[mf * 16 + lr][t * 32 + lg * 8]);
        acc[mf] = __builtin_amdgcn_mfma_f32_16x16x32_bf16(a, wf[t], acc[mf], 0, 0, 0);
      }
    }
#pragma unroll
    for (int mf = 0; mf < 4; ++mf)
#pragma unroll
      for (int r = 0; r < 4; ++r) {
        int node = node0 + mf * 16 + lg * 4 + r;
        if (node < NN) out[(size_t)node * OUT_D + n0 + lr] = acc[mf][r];
      }
  }
}

extern "C" void kernel_launch(void* const* d_in, const int* in_sizes, int n_in,
                              void* d_out, int out_size, void* d_ws, size_t ws_size,
                              hipStream_t stream) {
  const float* x   = (const float*)d_in[0];
  const int* ei    = (const int*)d_in[1];
  const float* ea  = (const float*)d_in[2];
  const float* u   = (const float*)d_in[3];
  const int* batch = (const int*)d_in[4];
  const float* W1  = (const float*)d_in[5];
  const float* b1  = (const float*)d_in[6];
  const float* W2  = (const float*)d_in[7];
  const float* b2  = (const float*)d_in[8];
  const float* W3  = (const float*)d_in[9];
  const float* b3  = (const float*)d_in[10];
  float* out = (float*)d_out;

  // workspace layout (~212 MB)
  unsigned short* ea16 = (unsigned short*)d_ws;            // NE*64 bf16 (204.8 MB, 128B rows)
  int* hist    = (int*)(ea16 + (size_t)NE * E16);          // NN
  int* offsets = hist + NN;                                // NN
  int* cursor  = offsets + NN;                             // NN
  int* perm    = cursor + NN;                              // NE (6.4 MB)
  int* bsum    = perm + NE;                                // SCAN_NB
  int* bpre    = bsum + SCAN_NB;                           // SCAN_NB
  unsigned short* Wp = (unsigned short*)(bpre + SCAN_NB + 60);  // NWTOT bf16

  const int wblocks = (NWTOT + 255) / 256;    // 176
  const int e4blocks = (NE / 4 + 255) / 256;  // 1563
  setup_kernel<<<SCAN_NB + wblocks, 256, 0, stream>>>(hist, W1, W2, W3, Wp);
  hist_pack_kernel<<<(NE + 255) / 256, 256, 0, stream>>>(ei, ea, hist, ea16);
  bsum_kernel<<<SCAN_NB, 256, 0, stream>>>(hist, bsum);
  bscan_kernel<<<1, 128, 0, stream>>>(bsum, bpre);
  offsets_kernel<<<SCAN_NB, 256, 0, stream>>>(hist, bpre, offsets, cursor);
  permute_kernel<<<e4blocks, 256, 0, stream>>>(ei, cursor, perm);
  fused_kernel<<<(NN + BM - 1) / BM, 256, 0, stream>>>(
      x, ea16, u, batch, perm, hist, offsets, Wp, b1, b2, b3, out);
}

// Round 15
// 281.802 us; speedup vs baseline: 1.6301x; 1.6301x over previous
//
#include <hip/hip_runtime.h>
#include <hip/hip_bf16.h>

#define NN 100000
#define NE 1600000
#define NODE_D 64
#define EDGE_D 48
#define E16 64   // padded ea16 row stride (bf16) = 128B = one full cache line
#define U_D 32
#define IN_D 144
#define HID 128
#define OUT_D 64
#define BM 64
#define S0 152   // act row stride (ushort cols)
#define SCAN_BS 1024
#define SCAN_NB ((NN + SCAN_BS - 1) / SCAN_BS)  // 98
#define W1K 160  // padded k-stride of packed W1 (zeros for k>=144)
#define NW1 (HID * W1K)      // 20480
#define NW2 (HID * HID)      // 16384
#define NW3 (OUT_D * HID)    // 8192
#define NWTOT (NW1 + NW2 + NW3)  // 45056
#define CH 16    // edges per wave-chunk in pack_scatter

typedef __attribute__((ext_vector_type(8))) short bf16x8;
typedef __attribute__((ext_vector_type(4))) float f32x4;
typedef __attribute__((ext_vector_type(4))) unsigned int u32x4;

__device__ __forceinline__ short f2bs(float f) {
  union { __hip_bfloat16 h; short s; } v;
  v.h = __float2bfloat16(f);
  return v.s;
}
__device__ __forceinline__ float blo(unsigned int pk) {
  union { unsigned int u; float f; } v; v.u = pk << 16; return v.f;
}
__device__ __forceinline__ float bhi(unsigned int pk) {
  union { unsigned int u; float f; } v; v.u = pk & 0xffff0000u; return v.f;
}
__device__ __forceinline__ unsigned pk2(float a, float b) {
  return (unsigned)(unsigned short)f2bs(a) | ((unsigned)(unsigned short)f2bs(b) << 16);
}

__device__ __forceinline__ void st4(unsigned short* p, float4 v) {
  *reinterpret_cast<uint2*>(p) = make_uint2(pk2(v.x, v.y), pk2(v.z, v.w));
}

// ---------------- setup: zero hist (blocks 0..97) + pack weights ----------------
__global__ __launch_bounds__(256) void setup_kernel(
    int* __restrict__ hist,
    const float* __restrict__ W1, const float* __restrict__ W2,
    const float* __restrict__ W3, unsigned short* __restrict__ Wp) {
  const int b = blockIdx.x, tid = threadIdx.x;
  if (b < SCAN_NB) {
    int base = b * SCAN_BS + tid * 4;
    if (base + 3 < NN) {
      *reinterpret_cast<int4*>(&hist[base]) = make_int4(0, 0, 0, 0);
    } else {
      for (int k = 0; k < 4; ++k)
        if (base + k < NN) hist[base + k] = 0;
    }
    return;
  }
  int gid = (b - SCAN_NB) * 256 + tid;
  if (gid >= NWTOT) return;
  float v;
  if (gid < NW1) {
    int n = gid / W1K, k = gid - n * W1K;
    v = (k < IN_D) ? W1[(size_t)k * HID + n] : 0.f;
  } else if (gid < NW1 + NW2) {
    int i2 = gid - NW1;
    int n = i2 >> 7, k = i2 & 127;
    v = W2[(size_t)k * HID + n];
  } else {
    int i3 = gid - NW1 - NW2;
    int n = i3 >> 7, k = i3 & 127;
    v = W3[(size_t)k * OUT_D + n];
  }
  Wp[gid] = (unsigned short)f2bs(v);
}

// ---------------- hist: 4 edges/thread ----------------
__global__ __launch_bounds__(256) void hist_kernel(const int* __restrict__ src,
                                                   int* __restrict__ hist) {
  int i = blockIdx.x * 256 + threadIdx.x;
  if (i * 4 >= NE) return;
  int4 s = reinterpret_cast<const int4*>(src)[i];
  atomicAdd(&hist[s.x], 1);
  atomicAdd(&hist[s.y], 1);
  atomicAdd(&hist[s.z], 1);
  atomicAdd(&hist[s.w], 1);
}

// ---------------- scan 2a ----------------
__global__ __launch_bounds__(256) void bsum_kernel(const int* __restrict__ hist,
                                                   int* __restrict__ bsum) {
  const int b = blockIdx.x, tid = threadIdx.x;
  const int base = b * SCAN_BS + tid * 4;
  int4 v = make_int4(0, 0, 0, 0);
  if (base + 3 < NN) v = *reinterpret_cast<const int4*>(&hist[base]);
  else {
    int t[4] = {0, 0, 0, 0};
    for (int k = 0; k < 4; ++k) if (base + k < NN) t[k] = hist[base + k];
    v = make_int4(t[0], t[1], t[2], t[3]);
  }
  int s = v.x + v.y + v.z + v.w;
  for (int d = 32; d; d >>= 1) s += __shfl_down(s, d, 64);
  __shared__ int ws[4];
  if ((tid & 63) == 0) ws[tid >> 6] = s;
  __syncthreads();
  if (tid == 0) bsum[b] = ws[0] + ws[1] + ws[2] + ws[3];
}

// ---------------- scan 2b ----------------
__global__ __launch_bounds__(128) void bscan_kernel(const int* __restrict__ bsum,
                                                    int* __restrict__ bpre) {
  const int t = threadIdx.x;
  const int lane = t & 63, wave = t >> 6;
  int v = (t < SCAN_NB) ? bsum[t] : 0;
  int incl = v;
  for (int d = 1; d < 64; d <<= 1) {
    int q = __shfl_up(incl, d, 64);
    if (lane >= d) incl += q;
  }
  __shared__ int wtot[2];
  if (lane == 63) wtot[wave] = incl;
  __syncthreads();
  int add = (wave == 1) ? wtot[0] : 0;
  if (t < SCAN_NB) bpre[t] = incl - v + add;
}

// ---------------- scan 2c ----------------
__global__ __launch_bounds__(256) void offsets_kernel(const int* __restrict__ hist,
                                                      const int* __restrict__ bpre,
                                                      int* __restrict__ offsets,
                                                      int* __restrict__ cursor) {
  const int b = blockIdx.x, tid = threadIdx.x;
  const int base = b * SCAN_BS + tid * 4;
  const int lane = tid & 63, wave = tid >> 6;
  int4 v = make_int4(0, 0, 0, 0);
  if (base + 3 < NN) v = *reinterpret_cast<const int4*>(&hist[base]);
  else {
    int t[4] = {0, 0, 0, 0};
    for (int k = 0; k < 4; ++k) if (base + k < NN) t[k] = hist[base + k];
    v = make_int4(t[0], t[1], t[2], t[3]);
  }
  const int tsum = v.x + v.y + v.z + v.w;
  int incl = tsum;
  for (int d = 1; d < 64; d <<= 1) {
    int q = __shfl_up(incl, d, 64);
    if (lane >= d) incl += q;
  }
  __shared__ int ws[4];
  __shared__ int wpre[4];
  if (lane == 63) ws[wave] = incl;
  __syncthreads();
  if (tid == 0) {
    int r = 0;
    for (int w = 0; w < 4; ++w) { wpre[w] = r; r += ws[w]; }
  }
  __syncthreads();
  int run = bpre[b] + wpre[wave] + incl - tsum;
  int vals[4] = {v.x, v.y, v.z, v.w};
  for (int k = 0; k < 4; ++k) {
    int i = base + k;
    if (i < NN) { offsets[i] = run; cursor[i] = run; run += vals[k]; }
  }
}

// ---------------- pack_scatter: wave-cooperative read + bf16 full-line scatter ----------------
// Per wave-iter: 16 edges. Read = 3 fully-coalesced dwordx4 loads (contig 3KB).
// Write = 2 store passes; each row's 128B line covered by 8 consecutive lanes.
__global__ __launch_bounds__(256) void pack_scatter_kernel(
    const int* __restrict__ src, const float* __restrict__ ea,
    int* __restrict__ cursor, unsigned short* __restrict__ ea16) {
  __shared__ float stage[4][CH * EDGE_D];  // 3KB per wave
  __shared__ int posbuf[4][CH];
  const int wid = threadIdx.x >> 6;
  const int lane = threadIdx.x & 63;
  float* st = stage[wid];
  int* pos = posbuf[wid];
  const int nchunks = NE / CH;  // 100000
  const int stride = gridDim.x * 4;
  for (int ch = blockIdx.x * 4 + wid; ch < nchunks; ch += stride) {
    const int e0 = ch * CH;
    if (lane < CH) {
      int s = src[e0 + lane];
      pos[lane] = atomicAdd(&cursor[s], 1);
    }
    const float4* gsrc = reinterpret_cast<const float4*>(ea + (size_t)e0 * EDGE_D);
    float4 v0 = gsrc[lane];
    float4 v1 = gsrc[lane + 64];
    float4 v2 = gsrc[lane + 128];
    float4* stv = reinterpret_cast<float4*>(st);
    stv[lane] = v0;
    stv[lane + 64] = v1;
    stv[lane + 128] = v2;
    // same-wave LDS RAW: in-order, compiler inserts lgkmcnt; no barrier needed
#pragma unroll
    for (int pass = 0; pass < 2; ++pass) {
      int t = pass * 64 + lane;
      int r = t >> 3, c = t & 7;
      u32x4 w = {0u, 0u, 0u, 0u};
      if (c < 6) {
        const float* f = st + r * EDGE_D + c * 8;
        w.x = pk2(f[0], f[1]);
        w.y = pk2(f[2], f[3]);
        w.z = pk2(f[4], f[5]);
        w.w = pk2(f[6], f[7]);
      }
      int p = pos[r];
      *reinterpret_cast<u32x4*>(ea16 + (size_t)p * E16 + c * 8) = w;
    }
  }
}

// ---------------- fused: sorted sequential bf16 gather + concat + 3-layer MLP ----------------
__global__ __launch_bounds__(256) void fused_kernel(
    const float* __restrict__ x, const unsigned short* __restrict__ ea16,
    const float* __restrict__ u, const int* __restrict__ batch,
    const int* __restrict__ hist, const int* __restrict__ offsets,
    const unsigned short* __restrict__ Wp,
    const float* __restrict__ b1, const float* __restrict__ b2,
    const float* __restrict__ b3, float* __restrict__ out) {
  __shared__ __align__(16) unsigned short act[BM][S0];  // comb -> h1 -> h2

  const int tid = threadIdx.x;
  const int lane = tid & 63;
  const int wid = tid >> 6;
  const int lr = lane & 15;
  const int lg = lane >> 4;
  const int node0 = blockIdx.x * BM;

  const unsigned short* Wp1 = Wp;                 // [HID][W1K]
  const unsigned short* Wp2 = Wp + NW1;           // [HID][HID]
  const unsigned short* Wp3 = Wp + NW1 + NW2;     // [OUT_D][HID]

  const bf16x8 az = {0, 0, 0, 0, 0, 0, 0, 0};

  // ---- stage x and u parts of comb ----
  for (int i = tid; i < BM * (NODE_D / 4); i += 256) {
    int r = i >> 4, q = i & 15;
    int node = node0 + r;
    float4 v = make_float4(0.f, 0.f, 0.f, 0.f);
    if (node < NN) v = reinterpret_cast<const float4*>(x)[(size_t)node * 16 + q];
    st4(&act[r][q * 4], v);
  }
  for (int i = tid; i < BM * (U_D / 4); i += 256) {
    int r = i >> 3, q = i & 7;
    int node = node0 + r;
    float4 v = make_float4(0.f, 0.f, 0.f, 0.f);
    if (node < NN) {
      int b = batch[node];
      v = reinterpret_cast<const float4*>(u)[(size_t)b * 8 + q];
    }
    st4(&act[r][NODE_D + EDGE_D + q * 4], v);
  }

  // ---- gather: 16-lane group per node; rows contiguous bf16, 128B stride ----
  {
    const int g = tid >> 4;        // group 0..15
    const int c = tid & 15;        // uint2 column (cols 12-15 read zero pad)
    for (int i = 0; i < 4; ++i) {
      const int nl = g * 4 + i;
      const int node = node0 + nl;
      int deg = 0, off = 0;
      if (node < NN) { deg = hist[node]; off = offsets[node]; }
      const unsigned short* rp = ea16 + (size_t)off * E16 + c * 4;
      float4 a0 = make_float4(0.f, 0.f, 0.f, 0.f);
      float4 a1 = make_float4(0.f, 0.f, 0.f, 0.f);
      int j = 0;
      for (; j + 7 < deg; j += 8) {
        uint2 w0 = *reinterpret_cast<const uint2*>(rp + (size_t)(j + 0) * E16);
        uint2 w1 = *reinterpret_cast<const uint2*>(rp + (size_t)(j + 1) * E16);
        uint2 w2 = *reinterpret_cast<const uint2*>(rp + (size_t)(j + 2) * E16);
        uint2 w3 = *reinterpret_cast<const uint2*>(rp + (size_t)(j + 3) * E16);
        uint2 w4 = *reinterpret_cast<const uint2*>(rp + (size_t)(j + 4) * E16);
        uint2 w5 = *reinterpret_cast<const uint2*>(rp + (size_t)(j + 5) * E16);
        uint2 w6 = *reinterpret_cast<const uint2*>(rp + (size_t)(j + 6) * E16);
        uint2 w7 = *reinterpret_cast<const uint2*>(rp + (size_t)(j + 7) * E16);
        a0.x += blo(w0.x) + blo(w1.x) + blo(w2.x) + blo(w3.x);
        a0.y += bhi(w0.x) + bhi(w1.x) + bhi(w2.x) + bhi(w3.x);
        a0.z += blo(w0.y) + blo(w1.y) + blo(w2.y) + blo(w3.y);
        a0.w += bhi(w0.y) + bhi(w1.y) + bhi(w2.y) + bhi(w3.y);
        a1.x += blo(w4.x) + blo(w5.x) + blo(w6.x) + blo(w7.x);
        a1.y += bhi(w4.x) + bhi(w5.x) + bhi(w6.x) + bhi(w7.x);
        a1.z += blo(w4.y) + blo(w5.y) + blo(w6.y) + blo(w7.y);
        a1.w += bhi(w4.y) + bhi(w5.y) + bhi(w6.y) + bhi(w7.y);
      }
      for (; j < deg; ++j) {
        uint2 w0 = *reinterpret_cast<const uint2*>(rp + (size_t)j * E16);
        a0.x += blo(w0.x); a0.y += bhi(w0.x);
        a0.z += blo(w0.y); a0.w += bhi(w0.y);
      }
      float inv = (deg > 0) ? 1.0f / (float)deg : 0.0f;
      if (c < 12 && node < NN)
        st4(&act[nl][NODE_D + c * 4],
            make_float4((a0.x + a1.x) * inv, (a0.y + a1.y) * inv,
                        (a0.z + a1.z) * inv, (a0.w + a1.w) * inv));
    }
  }
  __syncthreads();

  // ---- layer 1: [64,144] @ [144,128] + b1, relu ----
  {
    const int n0 = wid * 32;
    bf16x8 wf[5][2];
#pragma unroll
    for (int t = 0; t < 5; ++t)
#pragma unroll
      for (int nf = 0; nf < 2; ++nf)
        wf[t][nf] = *reinterpret_cast<const bf16x8*>(
            &Wp1[(size_t)(n0 + nf * 16 + lr) * W1K + t * 32 + lg * 8]);
    float bias0 = b1[n0 + lr], bias1 = b1[n0 + 16 + lr];
    f32x4 acc[4][2];
#pragma unroll
    for (int mf = 0; mf < 4; ++mf) {
      acc[mf][0] = (f32x4){bias0, bias0, bias0, bias0};
      acc[mf][1] = (f32x4){bias1, bias1, bias1, bias1};
    }
#pragma unroll
    for (int t = 0; t < 5; ++t) {
#pragma unroll
      for (int mf = 0; mf < 4; ++mf) {
        bf16x8 a;
        if (t < 4) {
          a = *reinterpret_cast<const bf16x8*>(&act[mf * 16 + lr][t * 32 + lg * 8]);
        } else {
          a = az;
          if (lg < 2)
            a = *reinterpret_cast<const bf16x8*>(&act[mf * 16 + lr][128 + lg * 8]);
        }
        acc[mf][0] = __builtin_amdgcn_mfma_f32_16x16x32_bf16(a, wf[t][0], acc[mf][0], 0, 0, 0);
        acc[mf][1] = __builtin_amdgcn_mfma_f32_16x16x32_bf16(a, wf[t][1], acc[mf][1], 0, 0, 0);
      }
    }
    __syncthreads();  // all waves done reading comb
#pragma unroll
    for (int mf = 0; mf < 4; ++mf)
#pragma unroll
      for (int nf = 0; nf < 2; ++nf)
#pragma unroll
        for (int r = 0; r < 4; ++r)
          act[mf * 16 + lg * 4 + r][n0 + nf * 16 + lr] =
              (unsigned short)f2bs(fmaxf(acc[mf][nf][r], 0.f));
  }
  __syncthreads();

  // ---- layer 2: [64,128] @ [128,128] + b2, relu ----
  {
    const int n0 = wid * 32;
    bf16x8 wf[4][2];
#pragma unroll
    for (int t = 0; t < 4; ++t)
#pragma unroll
      for (int nf = 0; nf < 2; ++nf)
        wf[t][nf] = *reinterpret_cast<const bf16x8*>(
            &Wp2[(size_t)(n0 + nf * 16 + lr) * HID + t * 32 + lg * 8]);
    float bias0 = b2[n0 + lr], bias1 = b2[n0 + 16 + lr];
    f32x4 acc[4][2];
#pragma unroll
    for (int mf = 0; mf < 4; ++mf) {
      acc[mf][0] = (f32x4){bias0, bias0, bias0, bias0};
      acc[mf][1] = (f32x4){bias1, bias1, bias1, bias1};
    }
#pragma unroll
    for (int t = 0; t < 4; ++t) {
#pragma unroll
      for (int mf = 0; mf < 4; ++mf) {
        bf16x8 a = *reinterpret_cast<const bf16x8*>(&act[mf * 16 + lr][t * 32 + lg * 8]);
        acc[mf][0] = __builtin_amdgcn_mfma_f32_16x16x32_bf16(a, wf[t][0], acc[mf][0], 0, 0, 0);
        acc[mf][1] = __builtin_amdgcn_mfma_f32_16x16x32_bf16(a, wf[t][1], acc[mf][1], 0, 0, 0);
      }
    }
    __syncthreads();  // all waves done reading h1
#pragma unroll
    for (int mf = 0; mf < 4; ++mf)
#pragma unroll
      for (int nf = 0; nf < 2; ++nf)
#pragma unroll
        for (int r = 0; r < 4; ++r)
          act[mf * 16 + lg * 4 + r][n0 + nf * 16 + lr] =
              (unsigned short)f2bs(fmaxf(acc[mf][nf][r], 0.f));
  }
  __syncthreads();

  // ---- layer 3: [64,128] @ [128,64] + b3 -> out (f32) ----
  {
    const int n0 = wid * 16;
    bf16x8 wf[4];
#pragma unroll
    for (int t = 0; t < 4; ++t)
      wf[t] = *reinterpret_cast<const bf16x8*>(
          &Wp3[(size_t)(n0 + lr) * HID + t * 32 + lg * 8]);
    float bias = b3[n0 + lr];
    f32x4 acc[4];
#pragma unroll
    for (int mf = 0; mf < 4; ++mf) acc[mf] = (f32x4){bias, bias, bias, bias};
#pragma unroll
    for (int t = 0; t < 4; ++t) {
#pragma unroll
      for (int mf = 0; mf < 4; ++mf) {
        bf16x8 a = *reinterpret_cast<const bf16x8*>(&act[mf * 16 + lr][t * 32 + lg * 8]);
        acc[mf] = __builtin_amdgcn_mfma_f32_16x16x32_bf16(a, wf[t], acc[mf], 0, 0, 0);
      }
    }
#pragma unroll
    for (int mf = 0; mf < 4; ++mf)
#pragma unroll
      for (int r = 0; r < 4; ++r) {
        int node = node0 + mf * 16 + lg * 4 + r;
        if (node < NN) out[(size_t)node * OUT_D + n0 + lr] = acc[mf][r];
      }
  }
}

extern "C" void kernel_launch(void* const* d_in, const int* in_sizes, int n_in,
                              void* d_out, int out_size, void* d_ws, size_t ws_size,
                              hipStream_t stream) {
  const float* x   = (const float*)d_in[0];
  const int* ei    = (const int*)d_in[1];
  const float* ea  = (const float*)d_in[2];
  const float* u   = (const float*)d_in[3];
  const int* batch = (const int*)d_in[4];
  const float* W1  = (const float*)d_in[5];
  const float* b1  = (const float*)d_in[6];
  const float* W2  = (const float*)d_in[7];
  const float* b2  = (const float*)d_in[8];
  const float* W3  = (const float*)d_in[9];
  const float* b3  = (const float*)d_in[10];
  float* out = (float*)d_out;

  // workspace layout (~206 MB)
  unsigned short* ea16 = (unsigned short*)d_ws;            // NE*64 bf16 (204.8 MB, 128B rows)
  int* hist    = (int*)(ea16 + (size_t)NE * E16);          // NN
  int* offsets = hist + NN;                                // NN
  int* cursor  = offsets + NN;                             // NN
  int* bsum    = cursor + NN;                              // SCAN_NB
  int* bpre    = bsum + SCAN_NB;                           // SCAN_NB
  unsigned short* Wp = (unsigned short*)(bpre + SCAN_NB + 60);  // NWTOT bf16

  const int wblocks = (NWTOT + 255) / 256;    // 176
  const int e4blocks = (NE / 4 + 255) / 256;  // 1563
  setup_kernel<<<SCAN_NB + wblocks, 256, 0, stream>>>(hist, W1, W2, W3, Wp);
  hist_kernel<<<e4blocks, 256, 0, stream>>>(ei, hist);
  bsum_kernel<<<SCAN_NB, 256, 0, stream>>>(hist, bsum);
  bscan_kernel<<<1, 128, 0, stream>>>(bsum, bpre);
  offsets_kernel<<<SCAN_NB, 256, 0, stream>>>(hist, bpre, offsets, cursor);
  pack_scatter_kernel<<<2048, 256, 0, stream>>>(ei, ea, cursor, ea16);
  fused_kernel<<<(NN + BM - 1) / BM, 256, 0, stream>>>(
      x, ea16, u, batch, hist, offsets, Wp, b1, b2, b3, out);
}

// Round 16
// 277.675 us; speedup vs baseline: 1.6543x; 1.0149x over previous
//
#include <hip/hip_runtime.h>
#include <hip/hip_bf16.h>

#define NN 100000
#define NE 1600000
#define NODE_D 64
#define EDGE_D 48
#define E16 64   // padded ea16 row stride (bf16) = 128B = one full cache line
#define U_D 32
#define IN_D 144
#define HID 128
#define OUT_D 64
#define BM 64
#define S0 152   // act row stride (ushort cols)
#define SCAN_BS 1024
#define SCAN_NB ((NN + SCAN_BS - 1) / SCAN_BS)  // 98
#define W1K 160  // padded k-stride of packed W1 (zeros for k>=144)
#define NW1 (HID * W1K)      // 20480
#define NW2 (HID * HID)      // 16384
#define NW3 (OUT_D * HID)    // 8192
#define NWTOT (NW1 + NW2 + NW3)  // 45056
#define CH 32    // edges per wave-chunk in pack_scatter

typedef __attribute__((ext_vector_type(8))) short bf16x8;
typedef __attribute__((ext_vector_type(4))) float f32x4;
typedef __attribute__((ext_vector_type(4))) unsigned int u32x4;

__device__ __forceinline__ short f2bs(float f) {
  union { __hip_bfloat16 h; short s; } v;
  v.h = __float2bfloat16(f);
  return v.s;
}
__device__ __forceinline__ float blo(unsigned int pk) {
  union { unsigned int u; float f; } v; v.u = pk << 16; return v.f;
}
__device__ __forceinline__ float bhi(unsigned int pk) {
  union { unsigned int u; float f; } v; v.u = pk & 0xffff0000u; return v.f;
}
__device__ __forceinline__ unsigned pk2(float a, float b) {
  return (unsigned)(unsigned short)f2bs(a) | ((unsigned)(unsigned short)f2bs(b) << 16);
}

__device__ __forceinline__ void st4(unsigned short* p, float4 v) {
  *reinterpret_cast<uint2*>(p) = make_uint2(pk2(v.x, v.y), pk2(v.z, v.w));
}

// ---------------- setup: zero hist (blocks 0..97) + pack weights ----------------
__global__ __launch_bounds__(256) void setup_kernel(
    int* __restrict__ hist,
    const float* __restrict__ W1, const float* __restrict__ W2,
    const float* __restrict__ W3, unsigned short* __restrict__ Wp) {
  const int b = blockIdx.x, tid = threadIdx.x;
  if (b < SCAN_NB) {
    int base = b * SCAN_BS + tid * 4;
    if (base + 3 < NN) {
      *reinterpret_cast<int4*>(&hist[base]) = make_int4(0, 0, 0, 0);
    } else {
      for (int k = 0; k < 4; ++k)
        if (base + k < NN) hist[base + k] = 0;
    }
    return;
  }
  int gid = (b - SCAN_NB) * 256 + tid;
  if (gid >= NWTOT) return;
  float v;
  if (gid < NW1) {
    int n = gid / W1K, k = gid - n * W1K;
    v = (k < IN_D) ? W1[(size_t)k * HID + n] : 0.f;
  } else if (gid < NW1 + NW2) {
    int i2 = gid - NW1;
    int n = i2 >> 7, k = i2 & 127;
    v = W2[(size_t)k * HID + n];
  } else {
    int i3 = gid - NW1 - NW2;
    int n = i3 >> 7, k = i3 & 127;
    v = W3[(size_t)k * OUT_D + n];
  }
  Wp[gid] = (unsigned short)f2bs(v);
}

// ---------------- hist: 4 edges/thread ----------------
__global__ __launch_bounds__(256) void hist_kernel(const int* __restrict__ src,
                                                   int* __restrict__ hist) {
  int i = blockIdx.x * 256 + threadIdx.x;
  if (i * 4 >= NE) return;
  int4 s = reinterpret_cast<const int4*>(src)[i];
  atomicAdd(&hist[s.x], 1);
  atomicAdd(&hist[s.y], 1);
  atomicAdd(&hist[s.z], 1);
  atomicAdd(&hist[s.w], 1);
}

// ---------------- scan 2a: per-block sums ----------------
__global__ __launch_bounds__(256) void bsum_kernel(const int* __restrict__ hist,
                                                   int* __restrict__ bsum) {
  const int b = blockIdx.x, tid = threadIdx.x;
  const int base = b * SCAN_BS + tid * 4;
  int4 v = make_int4(0, 0, 0, 0);
  if (base + 3 < NN) v = *reinterpret_cast<const int4*>(&hist[base]);
  else {
    int t[4] = {0, 0, 0, 0};
    for (int k = 0; k < 4; ++k) if (base + k < NN) t[k] = hist[base + k];
    v = make_int4(t[0], t[1], t[2], t[3]);
  }
  int s = v.x + v.y + v.z + v.w;
  for (int d = 32; d; d >>= 1) s += __shfl_down(s, d, 64);
  __shared__ int ws[4];
  if ((tid & 63) == 0) ws[tid >> 6] = s;
  __syncthreads();
  if (tid == 0) bsum[b] = ws[0] + ws[1] + ws[2] + ws[3];
}

// ---------------- scan 2b+2c merged: block prefix (wave-reduce) + offsets ----------------
__global__ __launch_bounds__(256) void offsets_kernel(const int* __restrict__ hist,
                                                      const int* __restrict__ bsum,
                                                      int* __restrict__ offsets,
                                                      int* __restrict__ cursor) {
  const int b = blockIdx.x, tid = threadIdx.x;
  const int base = b * SCAN_BS + tid * 4;
  const int lane = tid & 63, wave = tid >> 6;
  __shared__ int bprefix;
  __shared__ int ws[4];
  __shared__ int wpre[4];
  // wave 0: bprefix = sum_{i<b} bsum[i]
  if (wave == 0) {
    int s = 0;
    for (int i = lane; i < b; i += 64) s += bsum[i];
    for (int d = 32; d; d >>= 1) s += __shfl_down(s, d, 64);
    if (lane == 0) bprefix = s;
  }
  int4 v = make_int4(0, 0, 0, 0);
  if (base + 3 < NN) v = *reinterpret_cast<const int4*>(&hist[base]);
  else {
    int t[4] = {0, 0, 0, 0};
    for (int k = 0; k < 4; ++k) if (base + k < NN) t[k] = hist[base + k];
    v = make_int4(t[0], t[1], t[2], t[3]);
  }
  const int tsum = v.x + v.y + v.z + v.w;
  int incl = tsum;
  for (int d = 1; d < 64; d <<= 1) {
    int q = __shfl_up(incl, d, 64);
    if (lane >= d) incl += q;
  }
  if (lane == 63) ws[wave] = incl;
  __syncthreads();
  if (tid == 0) {
    int r = 0;
    for (int w = 0; w < 4; ++w) { wpre[w] = r; r += ws[w]; }
  }
  __syncthreads();
  int run = bprefix + wpre[wave] + incl - tsum;
  int vals[4] = {v.x, v.y, v.z, v.w};
  for (int k = 0; k < 4; ++k) {
    int i = base + k;
    if (i < NN) { offsets[i] = run; cursor[i] = run; run += vals[k]; }
  }
}

// ---------------- pack_scatter: wave-cooperative read + bf16 full-line scatter ----------------
// Per wave-iter: 32 edges. Read = 6 fully-coalesced dwordx4 loads (contig 6KB).
// Write = 4 store passes; each row's 128B line covered by 8 consecutive lanes.
__global__ __launch_bounds__(256) void pack_scatter_kernel(
    const int* __restrict__ src, const float* __restrict__ ea,
    int* __restrict__ cursor, unsigned short* __restrict__ ea16) {
  __shared__ float stage[4][CH * EDGE_D];  // 4 x 6KB
  __shared__ int posbuf[4][CH];
  const int wid = threadIdx.x >> 6;
  const int lane = threadIdx.x & 63;
  float* st = stage[wid];
  int* pos = posbuf[wid];
  const int nchunks = NE / CH;  // 50000
  const int stride = gridDim.x * 4;
  for (int ch = blockIdx.x * 4 + wid; ch < nchunks; ch += stride) {
    const int e0 = ch * CH;
    if (lane < CH) {
      int s = src[e0 + lane];
      pos[lane] = atomicAdd(&cursor[s], 1);
    }
    const float4* gsrc = reinterpret_cast<const float4*>(ea + (size_t)e0 * EDGE_D);
    float4 v[6];
#pragma unroll
    for (int k = 0; k < 6; ++k) v[k] = gsrc[lane + k * 64];
    float4* stv = reinterpret_cast<float4*>(st);
#pragma unroll
    for (int k = 0; k < 6; ++k) stv[lane + k * 64] = v[k];
    // fence: all LDS writes (stage + pos) drained before cross-lane reads
    asm volatile("s_waitcnt lgkmcnt(0)" ::: "memory");
    __builtin_amdgcn_sched_barrier(0);
#pragma unroll
    for (int pass = 0; pass < 4; ++pass) {
      int t = pass * 64 + lane;
      int r = t >> 3, c = t & 7;
      u32x4 w = {0u, 0u, 0u, 0u};
      if (c < 6) {
        const float* f = st + r * EDGE_D + c * 8;
        w.x = pk2(f[0], f[1]);
        w.y = pk2(f[2], f[3]);
        w.z = pk2(f[4], f[5]);
        w.w = pk2(f[6], f[7]);
      }
      int p = pos[r];
      *reinterpret_cast<u32x4*>(ea16 + (size_t)p * E16 + c * 8) = w;
    }
    // LDS reads of this iter complete before next iter's writes (same-wave order)
    asm volatile("s_waitcnt lgkmcnt(0)" ::: "memory");
    __builtin_amdgcn_sched_barrier(0);
  }
}

// ---------------- fused: sorted sequential bf16 gather + concat + 3-layer MLP ----------------
__global__ __launch_bounds__(256) void fused_kernel(
    const float* __restrict__ x, const unsigned short* __restrict__ ea16,
    const float* __restrict__ u, const int* __restrict__ batch,
    const int* __restrict__ hist, const int* __restrict__ offsets,
    const unsigned short* __restrict__ Wp,
    const float* __restrict__ b1, const float* __restrict__ b2,
    const float* __restrict__ b3, float* __restrict__ out) {
  __shared__ __align__(16) unsigned short act[BM][S0];  // comb -> h1 -> h2

  const int tid = threadIdx.x;
  const int lane = tid & 63;
  const int wid = tid >> 6;
  const int lr = lane & 15;
  const int lg = lane >> 4;
  const int node0 = blockIdx.x * BM;

  const unsigned short* Wp1 = Wp;                 // [HID][W1K]
  const unsigned short* Wp2 = Wp + NW1;           // [HID][HID]
  const unsigned short* Wp3 = Wp + NW1 + NW2;     // [OUT_D][HID]

  const bf16x8 az = {0, 0, 0, 0, 0, 0, 0, 0};

  // ---- stage x and u parts of comb ----
  for (int i = tid; i < BM * (NODE_D / 4); i += 256) {
    int r = i >> 4, q = i & 15;
    int node = node0 + r;
    float4 v = make_float4(0.f, 0.f, 0.f, 0.f);
    if (node < NN) v = reinterpret_cast<const float4*>(x)[(size_t)node * 16 + q];
    st4(&act[r][q * 4], v);
  }
  for (int i = tid; i < BM * (U_D / 4); i += 256) {
    int r = i >> 3, q = i & 7;
    int node = node0 + r;
    float4 v = make_float4(0.f, 0.f, 0.f, 0.f);
    if (node < NN) {
      int b = batch[node];
      v = reinterpret_cast<const float4*>(u)[(size_t)b * 8 + q];
    }
    st4(&act[r][NODE_D + EDGE_D + q * 4], v);
  }

  // ---- gather: 16-lane group per node; rows contiguous bf16, 128B stride ----
  {
    const int g = tid >> 4;        // group 0..15
    const int c = tid & 15;        // uint2 column (cols 12-15 read zero pad)
    for (int i = 0; i < 4; ++i) {
      const int nl = g * 4 + i;
      const int node = node0 + nl;
      int deg = 0, off = 0;
      if (node < NN) { deg = hist[node]; off = offsets[node]; }
      const unsigned short* rp = ea16 + (size_t)off * E16 + c * 4;
      float4 a0 = make_float4(0.f, 0.f, 0.f, 0.f);
      float4 a1 = make_float4(0.f, 0.f, 0.f, 0.f);
      int j = 0;
      for (; j + 7 < deg; j += 8) {
        uint2 w0 = *reinterpret_cast<const uint2*>(rp + (size_t)(j + 0) * E16);
        uint2 w1 = *reinterpret_cast<const uint2*>(rp + (size_t)(j + 1) * E16);
        uint2 w2 = *reinterpret_cast<const uint2*>(rp + (size_t)(j + 2) * E16);
        uint2 w3 = *reinterpret_cast<const uint2*>(rp + (size_t)(j + 3) * E16);
        uint2 w4 = *reinterpret_cast<const uint2*>(rp + (size_t)(j + 4) * E16);
        uint2 w5 = *reinterpret_cast<const uint2*>(rp + (size_t)(j + 5) * E16);
        uint2 w6 = *reinterpret_cast<const uint2*>(rp + (size_t)(j + 6) * E16);
        uint2 w7 = *reinterpret_cast<const uint2*>(rp + (size_t)(j + 7) * E16);
        a0.x += blo(w0.x) + blo(w1.x) + blo(w2.x) + blo(w3.x);
        a0.y += bhi(w0.x) + bhi(w1.x) + bhi(w2.x) + bhi(w3.x);
        a0.z += blo(w0.y) + blo(w1.y) + blo(w2.y) + blo(w3.y);
        a0.w += bhi(w0.y) + bhi(w1.y) + bhi(w2.y) + bhi(w3.y);
        a1.x += blo(w4.x) + blo(w5.x) + blo(w6.x) + blo(w7.x);
        a1.y += bhi(w4.x) + bhi(w5.x) + bhi(w6.x) + bhi(w7.x);
        a1.z += blo(w4.y) + blo(w5.y) + blo(w6.y) + blo(w7.y);
        a1.w += bhi(w4.y) + bhi(w5.y) + bhi(w6.y) + bhi(w7.y);
      }
      for (; j < deg; ++j) {
        uint2 w0 = *reinterpret_cast<const uint2*>(rp + (size_t)j * E16);
        a0.x += blo(w0.x); a0.y += bhi(w0.x);
        a0.z += blo(w0.y); a0.w += bhi(w0.y);
      }
      float inv = (deg > 0) ? 1.0f / (float)deg : 0.0f;
      if (c < 12 && node < NN)
        st4(&act[nl][NODE_D + c * 4],
            make_float4((a0.x + a1.x) * inv, (a0.y + a1.y) * inv,
                        (a0.z + a1.z) * inv, (a0.w + a1.w) * inv));
    }
  }
  __syncthreads();

  // ---- layer 1: [64,144] @ [144,128] + b1, relu ----
  {
    const int n0 = wid * 32;
    bf16x8 wf[5][2];
#pragma unroll
    for (int t = 0; t < 5; ++t)
#pragma unroll
      for (int nf = 0; nf < 2; ++nf)
        wf[t][nf] = *reinterpret_cast<const bf16x8*>(
            &Wp1[(size_t)(n0 + nf * 16 + lr) * W1K + t * 32 + lg * 8]);
    float bias0 = b1[n0 + lr], bias1 = b1[n0 + 16 + lr];
    f32x4 acc[4][2];
#pragma unroll
    for (int mf = 0; mf < 4; ++mf) {
      acc[mf][0] = (f32x4){bias0, bias0, bias0, bias0};
      acc[mf][1] = (f32x4){bias1, bias1, bias1, bias1};
    }
#pragma unroll
    for (int t = 0; t < 5; ++t) {
#pragma unroll
      for (int mf = 0; mf < 4; ++mf) {
        bf16x8 a;
        if (t < 4) {
          a = *reinterpret_cast<const bf16x8*>(&act[mf * 16 + lr][t * 32 + lg * 8]);
        } else {
          a = az;
          if (lg < 2)
            a = *reinterpret_cast<const bf16x8*>(&act[mf * 16 + lr][128 + lg * 8]);
        }
        acc[mf][0] = __builtin_amdgcn_mfma_f32_16x16x32_bf16(a, wf[t][0], acc[mf][0], 0, 0, 0);
        acc[mf][1] = __builtin_amdgcn_mfma_f32_16x16x32_bf16(a, wf[t][1], acc[mf][1], 0, 0, 0);
      }
    }
    __syncthreads();  // all waves done reading comb
#pragma unroll
    for (int mf = 0; mf < 4; ++mf)
#pragma unroll
      for (int nf = 0; nf < 2; ++nf)
#pragma unroll
        for (int r = 0; r < 4; ++r)
          act[mf * 16 + lg * 4 + r][n0 + nf * 16 + lr] =
              (unsigned short)f2bs(fmaxf(acc[mf][nf][r], 0.f));
  }
  __syncthreads();

  // ---- layer 2: [64,128] @ [128,128] + b2, relu ----
  {
    const int n0 = wid * 32;
    bf16x8 wf[4][2];
#pragma unroll
    for (int t = 0; t < 4; ++t)
#pragma unroll
      for (int nf = 0; nf < 2; ++nf)
        wf[t][nf] = *reinterpret_cast<const bf16x8*>(
            &Wp2[(size_t)(n0 + nf * 16 + lr) * HID + t * 32 + lg * 8]);
    float bias0 = b2[n0 + lr], bias1 = b2[n0 + 16 + lr];
    f32x4 acc[4][2];
#pragma unroll
    for (int mf = 0; mf < 4; ++mf) {
      acc[mf][0] = (f32x4){bias0, bias0, bias0, bias0};
      acc[mf][1] = (f32x4){bias1, bias1, bias1, bias1};
    }
#pragma unroll
    for (int t = 0; t < 4; ++t) {
#pragma unroll
      for (int mf = 0; mf < 4; ++mf) {
        bf16x8 a = *reinterpret_cast<const bf16x8*>(&act[mf * 16 + lr][t * 32 + lg * 8]);
        acc[mf][0] = __builtin_amdgcn_mfma_f32_16x16x32_bf16(a, wf[t][0], acc[mf][0], 0, 0, 0);
        acc[mf][1] = __builtin_amdgcn_mfma_f32_16x16x32_bf16(a, wf[t][1], acc[mf][1], 0, 0, 0);
      }
    }
    __syncthreads();  // all waves done reading h1
#pragma unroll
    for (int mf = 0; mf < 4; ++mf)
#pragma unroll
      for (int nf = 0; nf < 2; ++nf)
#pragma unroll
        for (int r = 0; r < 4; ++r)
          act[mf * 16 + lg * 4 + r][n0 + nf * 16 + lr] =
              (unsigned short)f2bs(fmaxf(acc[mf][nf][r], 0.f));
  }
  __syncthreads();

  // ---- layer 3: [64,128] @ [128,64] + b3 -> out (f32) ----
  {
    const int n0 = wid * 16;
    bf16x8 wf[4];
#pragma unroll
    for (int t = 0; t < 4; ++t)
      wf[t] = *reinterpret_cast<const bf16x8*>(
          &Wp3[(size_t)(n0 + lr) * HID + t * 32 + lg * 8]);
    float bias = b3[n0 + lr];
    f32x4 acc[4];
#pragma unroll
    for (int mf = 0; mf < 4; ++mf) acc[mf] = (f32x4){bias, bias, bias, bias};
#pragma unroll
    for (int t = 0; t < 4; ++t) {
#pragma unroll
      for (int mf = 0; mf < 4; ++mf) {
        bf16x8 a = *reinterpret_cast<const bf16x8*>(&act[mf * 16 + lr][t * 32 + lg * 8]);
        acc[mf] = __builtin_amdgcn_mfma_f32_16x16x32_bf16(a, wf[t], acc[mf], 0, 0, 0);
      }
    }
#pragma unroll
    for (int mf = 0; mf < 4; ++mf)
#pragma unroll
      for (int r = 0; r < 4; ++r) {
        int node = node0 + mf * 16 + lg * 4 + r;
        if (node < NN) out[(size_t)node * OUT_D + n0 + lr] = acc[mf][r];
      }
  }
}

extern "C" void kernel_launch(void* const* d_in, const int* in_sizes, int n_in,
                              void* d_out, int out_size, void* d_ws, size_t ws_size,
                              hipStream_t stream) {
  const float* x   = (const float*)d_in[0];
  const int* ei    = (const int*)d_in[1];
  const float* ea  = (const float*)d_in[2];
  const float* u   = (const float*)d_in[3];
  const int* batch = (const int*)d_in[4];
  const float* W1  = (const float*)d_in[5];
  const float* b1  = (const float*)d_in[6];
  const float* W2  = (const float*)d_in[7];
  const float* b2  = (const float*)d_in[8];
  const float* W3  = (const float*)d_in[9];
  const float* b3  = (const float*)d_in[10];
  float* out = (float*)d_out;

  // workspace layout (~206 MB)
  unsigned short* ea16 = (unsigned short*)d_ws;            // NE*64 bf16 (204.8 MB, 128B rows)
  int* hist    = (int*)(ea16 + (size_t)NE * E16);          // NN
  int* offsets = hist + NN;                                // NN
  int* cursor  = offsets + NN;                             // NN
  int* bsum    = cursor + NN;                              // SCAN_NB
  unsigned short* Wp = (unsigned short*)(bsum + SCAN_NB + 62);  // NWTOT bf16

  const int wblocks = (NWTOT + 255) / 256;    // 176
  const int e4blocks = (NE / 4 + 255) / 256;  // 1563
  setup_kernel<<<SCAN_NB + wblocks, 256, 0, stream>>>(hist, W1, W2, W3, Wp);
  hist_kernel<<<e4blocks, 256, 0, stream>>>(ei, hist);
  bsum_kernel<<<SCAN_NB, 256, 0, stream>>>(hist, bsum);
  offsets_kernel<<<SCAN_NB, 256, 0, stream>>>(hist, bsum, offsets, cursor);
  pack_scatter_kernel<<<1536, 256, 0, stream>>>(ei, ea, cursor, ea16);
  fused_kernel<<<(NN + BM - 1) / BM, 256, 0, stream>>>(
      x, ea16, u, batch, hist, offsets, Wp, b1, b2, b3, out);
}